// Round 11
// baseline (414.549 us; speedup 1.0000x reference)
//
#include <hip/hip_runtime.h>

typedef unsigned short u16;
typedef __attribute__((ext_vector_type(8))) short short8;
typedef __attribute__((ext_vector_type(4))) float f32x4;

#define A_ 4
#define T_ 128
#define B_ 256
#define OBS_ 128
#define H_ 128
#define G_ 384
#define ACT_ 8
#define SIGS -1.4426950408889634f
#define TANS 2.8853900817779268f

__device__ __forceinline__ u16 f2b(float x) {
    unsigned int u = __float_as_uint(x);
    u = (u + 0x7fffu + ((u >> 16) & 1u)) >> 16;
    return (u16)u;
}
__device__ __forceinline__ u16 f2bc(float x) {  // cheap RN (ties up) for hot loops
    return (u16)((__float_as_uint(x) + 0x8000u) >> 16);
}
__device__ __forceinline__ float fexp2_(float x) { return __builtin_amdgcn_exp2f(x); }
__device__ __forceinline__ float frcp_(float x) { return __builtin_amdgcn_rcpf(x); }
// prescaled forms: arg already multiplied by SIGS / TANS at weight-prep time
__device__ __forceinline__ float sig_pre(float x) { return frcp_(1.0f + fexp2_(x)); }
__device__ __forceinline__ float tanh_pre(float x) {
    return fmaf(-2.0f, frcp_(1.0f + fexp2_(x)), 1.0f);
}
__device__ __forceinline__ f32x4 mfma16(short8 a, short8 b, f32x4 c) {
    return __builtin_amdgcn_mfma_f32_16x16x32_bf16(a, b, c, 0, 0, 0);
}

// ---------------- K0: weight transpose/convert (+gate prescale) ------------
__global__ void k_prep(const float* __restrict__ We, const float* __restrict__ Wi,
                       const float* __restrict__ Wh, const float* __restrict__ Wa1,
                       const float* __restrict__ Wc1, const float* __restrict__ Wa2,
                       const float* __restrict__ Wc2, const float* __restrict__ log_std,
                       u16* __restrict__ weT, u16* __restrict__ wiT, u16* __restrict__ whT,
                       u16* __restrict__ wa1T, u16* __restrict__ wc1T, u16* __restrict__ h2T,
                       float* __restrict__ std_out) {
    const int PER_A = 149504;
    int idx = blockIdx.x * 256 + threadIdx.x;
    const int total = 4 * PER_A;
    if (idx < total) {
        int a = idx / PER_A;
        int i = idx % PER_A;
        if (i < 16384) {
            int h = i >> 7, o = i & 127;
            weT[a * 16384 + i] = f2b(TANS * We[a * 16384 + o * 128 + h]);
        } else if (i < 16384 + 49152) {
            int j = i - 16384; int g = j >> 7, k = j & 127;
            float s = (g < 256) ? SIGS : TANS;
            wiT[a * 49152 + j] = f2b(s * Wi[a * 49152 + k * 384 + g]);
        } else if (i < 16384 + 2 * 49152) {
            int j = i - 16384 - 49152; int g = j >> 7, k = j & 127;
            float s = (g < 256) ? SIGS : TANS;
            whT[a * 49152 + j] = f2b(s * Wh[a * 49152 + k * 384 + g]);
        } else if (i < 2 * 16384 + 2 * 49152) {
            int j = i - 16384 - 2 * 49152; int h2 = j >> 7, k = j & 127;
            wa1T[a * 16384 + j] = f2b(TANS * Wa1[a * 16384 + k * 128 + h2]);
        } else if (i < 3 * 16384 + 2 * 49152) {
            int j = i - 2 * 16384 - 2 * 49152; int h2 = j >> 7, k = j & 127;
            wc1T[a * 16384 + j] = f2b(TANS * Wc1[a * 16384 + k * 128 + h2]);
        } else {
            int j = i - 3 * 16384 - 2 * 49152; int row = j >> 7, k = j & 127;
            float v = 0.f;
            if (row < 8) v = Wa2[a * 1024 + k * 8 + row];
            else if (row == 8) v = Wc2[a * 128 + k];
            h2T[a * 2048 + j] = f2b(v);
        }
    } else if (idx < total + 32) {
        int i = idx - total;
        std_out[i] = __expf(log_std[i]);
    }
}

// ---------------- K1: GRU scan + FUSED embed/xi + FUSED heads --------------
// One kernel does everything per (a,btile): at step t it stages obs(t+1),
// computes emb(t+1) (4 MFMA -> elds, consumed next step), computes xi(t) by
// accumulating emb(t)@Wi DIRECTLY into the gate accumulators (ar/az merge Wi
// and Wh chains; xn/an separate per GRU semantics), runs the GRU gates, and
// the two head GEMMs (GEMM2 deferred one step). xi never touches global
// memory: kills k_embed_xi (~130us) and the 200 MB xi round-trip. Single
// barrier per step. All transcendental args prescaled at k_prep.
__global__ __launch_bounds__(512, 2) void k_scan(
    const float* __restrict__ hstate, const float* __restrict__ obs,
    const u16* __restrict__ weT, const u16* __restrict__ wiT,
    const u16* __restrict__ whT,
    const float* __restrict__ be, const float* __restrict__ bi,
    const float* __restrict__ bhn, const int* __restrict__ done,
    const u16* __restrict__ wa1T, const u16* __restrict__ wc1T, const u16* __restrict__ h2T,
    const float* __restrict__ ba1, const float* __restrict__ bc1,
    const float* __restrict__ ba2, const float* __restrict__ bc2,
    float* __restrict__ hT_out, float* __restrict__ mean_out, float* __restrict__ val_out) {
    __shared__ __align__(16) u16 hlds[2][16][136];
    __shared__ __align__(16) u16 obsl[2][16][136];
    __shared__ __align__(16) u16 elds[2][16][136];
    __shared__ __align__(16) u16 al[2][2][16][136];  // [t&1][head][row][col]
    const int a = blockIdx.y, btile = blockIdx.x;
    const int wid = threadIdx.x >> 6, lane = threadIdx.x & 63;
    const int m = lane & 15, quad = lane >> 4;
    const int b0 = btile * 16;
    const int col = 16 * wid + m;
    const int srow = threadIdx.x >> 5, schunk = threadIdx.x & 31;

    // ---- resident weights: Wh(48) + We(16) + Wi(48) + Wa1/Wc1/h2(48) VGPR
    short8 wh[3][4], we[4], wi[3][4], wa[4], wc[4], h2f[4];
    {
        const u16* whTa = whT + a * 49152;
#pragma unroll
        for (int g = 0; g < 3; ++g) {
            const u16* p = whTa + (g * 128 + col) * 128 + quad * 8;
#pragma unroll
            for (int ks = 0; ks < 4; ++ks) wh[g][ks] = *(const short8*)(p + ks * 32);
        }
        const u16* pe = weT + a * 16384 + col * 128 + quad * 8;
#pragma unroll
        for (int ks = 0; ks < 4; ++ks) we[ks] = *(const short8*)(pe + ks * 32);
#pragma unroll
        for (int g = 0; g < 3; ++g) {
            const u16* q = wiT + a * 49152 + (g * 128 + col) * 128 + quad * 8;
#pragma unroll
            for (int ks = 0; ks < 4; ++ks) wi[g][ks] = *(const short8*)(q + ks * 32);
        }
        const u16* pa = wa1T + a * 16384 + col * 128 + quad * 8;
        const u16* pc = wc1T + a * 16384 + col * 128 + quad * 8;
        const u16* ph = h2T + a * 2048 + m * 128 + quad * 8;
#pragma unroll
        for (int ks = 0; ks < 4; ++ks) {
            wa[ks] = *(const short8*)(pa + ks * 32);
            wc[ks] = *(const short8*)(pc + ks * 32);
            h2f[ks] = *(const short8*)(ph + ks * 32);
        }
    }
    const float bh = TANS * bhn[a * H_ + col];
    const float bee = TANS * be[a * H_ + col];
    const float bir = SIGS * bi[a * G_ + col];
    const float biz = SIGS * bi[a * G_ + 128 + col];
    const float bin = TANS * bi[a * G_ + 256 + col];
    const float fa = TANS * ba1[a * 128 + col];
    const float fc = TANS * bc1[a * 128 + col];
    float bb2 = 0.f;
    if (wid == 0) { if (m < 8) bb2 = ba2[a * 8 + m]; }
    else if (wid == 1) { if (m == 8) bb2 = bc2[a]; }

    float hm[4]; u16 hb[4];
#pragma unroll
    for (int r = 0; r < 4; ++r) {
        float v = hstate[((size_t)a * B_ + b0 + quad * 4 + r) * H_ + col];
        hm[r] = v; hb[r] = f2b(v);
    }

    const int* dptr = done + (size_t)a * T_ * B_ + b0 + quad * 4;   // C-layout rows
    const int* dAq = done + (size_t)a * T_ * B_ + b0 + m;           // A-layout row
    int4 dn = *(const int4*)(dptr);
    int dead = dAq[0];

    // obs: per-thread row b0+srow, chunk schunk*4; stride between t = B*OBS
    const float* obsrow = obs + ((size_t)a * T_ * B_ + b0 + srow) * OBS_ + schunk * 4;

    // ---- prologue: stage obs(0), emb(0) -> elds[0]; prefetch obs(1)
    {
        float4 p0 = *(const float4*)(obsrow);
        ushort4 ob;
        ob.x = f2b(p0.x); ob.y = f2b(p0.y); ob.z = f2b(p0.z); ob.w = f2b(p0.w);
        *(ushort4*)&obsl[0][srow][schunk * 4] = ob;
    }
    float4 pf = *(const float4*)(obsrow + (size_t)B_ * OBS_);
    __syncthreads();
    {
        short8 of[4];
#pragma unroll
        for (int ks = 0; ks < 4; ++ks)
            of[ks] = *(const short8*)&obsl[0][m][ks * 32 + quad * 8];
        f32x4 eacc = f32x4{bee, bee, bee, bee};
#pragma unroll
        for (int ks = 0; ks < 4; ++ks) eacc = mfma16(of[ks], we[ks], eacc);
#pragma unroll
        for (int r = 0; r < 4; ++r)
            elds[0][quad * 4 + r][col] = f2bc(tanh_pre(eacc[r]));
    }

    for (int t = 0; t < T_; ++t) {
        u16 (*hl)[136] = hlds[t & 1];
        // publish UNRESET ys(t-1); reset register copy for the z*h term
#pragma unroll
        for (int r = 0; r < 4; ++r) hl[quad * 4 + r][col] = hb[r];
        if (dn.x) hm[0] = 0.f;
        if (dn.y) hm[1] = 0.f;
        if (dn.z) hm[2] = 0.f;
        if (dn.w) hm[3] = 0.f;
        // stage obs(t+1) (loaded one step ago into pf)
        if (t + 1 < T_) {
            ushort4 ob;
            ob.x = f2b(pf.x); ob.y = f2b(pf.y); ob.z = f2b(pf.z); ob.w = f2b(pf.w);
            *(ushort4*)&obsl[(t + 1) & 1][srow][schunk * 4] = ob;
        }
        __syncthreads();   // the ONLY barrier per step

        const int deadcur = dead;
        // prefetch obs(t+2) + done(t+1)
        if (t + 2 < T_) pf = *(const float4*)(obsrow + (size_t)(t + 2) * B_ * OBS_);
        if (t + 1 < T_) {
            dn = *(const int4*)(dptr + (size_t)(t + 1) * B_);
            dead = dAq[(size_t)(t + 1) * B_];
        }

        // LDS fragment reads
        short8 af[4], ef[4];
#pragma unroll
        for (int ks = 0; ks < 4; ++ks) {
            af[ks] = *(const short8*)&hl[m][ks * 32 + quad * 8];
            ef[ks] = *(const short8*)&elds[t & 1][m][ks * 32 + quad * 8];
        }

        // heads first GEMMs on UNRESET ys(t-1) (af before masking)
        f32x4 aa, ac;
        if (t > 0) {
            aa = f32x4{fa, fa, fa, fa};
            ac = f32x4{fc, fc, fc, fc};
#pragma unroll
            for (int ks = 0; ks < 4; ++ks) {
                aa = mfma16(af[ks], wa[ks], aa);
                ac = mfma16(af[ks], wc[ks], ac);
            }
        }
        // done-reset for the Wh path — mask af in place, skip if none dead
        if (__any(deadcur)) {
            const short8 z8 = short8{0, 0, 0, 0, 0, 0, 0, 0};
#pragma unroll
            for (int ks = 0; ks < 4; ++ks) if (deadcur) af[ks] = z8;
        }

        // gate accumulators: xi(t) (from ef) and h@Wh (from af) merged
        f32x4 ar = f32x4{bir, bir, bir, bir};
        f32x4 az = f32x4{biz, biz, biz, biz};
        f32x4 xn = f32x4{bin, bin, bin, bin};
        f32x4 an = f32x4{bh, bh, bh, bh};
#pragma unroll
        for (int ks = 0; ks < 4; ++ks) {
            ar = mfma16(ef[ks], wi[0][ks], ar);
            az = mfma16(ef[ks], wi[1][ks], az);
            xn = mfma16(ef[ks], wi[2][ks], xn);
            an = mfma16(af[ks], wh[2][ks], an);
        }
#pragma unroll
        for (int ks = 0; ks < 4; ++ks) {
            ar = mfma16(af[ks], wh[0][ks], ar);
            az = mfma16(af[ks], wh[1][ks], az);
        }

        // emb(t+1): obs frags -> elds[(t+1)&1] (consumed next step)
        if (t + 1 < T_) {
            short8 of[4];
#pragma unroll
            for (int ks = 0; ks < 4; ++ks)
                of[ks] = *(const short8*)&obsl[(t + 1) & 1][m][ks * 32 + quad * 8];
            f32x4 eacc = f32x4{bee, bee, bee, bee};
#pragma unroll
            for (int ks = 0; ks < 4; ++ks) eacc = mfma16(of[ks], we[ks], eacc);
#pragma unroll
            for (int r = 0; r < 4; ++r)
                elds[(t + 1) & 1][quad * 4 + r][col] = f2bc(tanh_pre(eacc[r]));
        }

        // heads tanh -> LDS (read NEXT step; no extra barrier)
        if (t > 0) {
#pragma unroll
            for (int r = 0; r < 4; ++r) {
                al[t & 1][0][quad * 4 + r][col] = f2bc(tanh_pre(aa[r]));
                al[t & 1][1][quad * 4 + r][col] = f2bc(tanh_pre(ac[r]));
            }
        }

        // GRU gates (prescaled args; xi is full f32, never rounded)
#pragma unroll
        for (int r = 0; r < 4; ++r) {
            const float rg = sig_pre(ar[r]);
            const float zg = sig_pre(az[r]);
            const float ng = tanh_pre(fmaf(rg, an[r], xn[r]));
            const float hn2 = fmaf(zg, hm[r] - ng, ng);
            hm[r] = hn2;
            hb[r] = f2bc(hn2);
        }

        // deferred heads second GEMM: al[(t-1)&1] -> outputs for timestep t-2
        if (t >= 2 && wid < 2) {
            short8 tf[4];
#pragma unroll
            for (int ks = 0; ks < 4; ++ks)
                tf[ks] = *(const short8*)&al[(t - 1) & 1][wid][m][ks * 32 + quad * 8];
            f32x4 tacc = f32x4{bb2, bb2, bb2, bb2};
#pragma unroll
            for (int ks = 0; ks < 4; ++ks) tacc = mfma16(tf[ks], h2f[ks], tacc);
            const size_t R0 = (size_t)a * 32768 + (size_t)(t - 2) * 256 + b0;
            if (wid == 0) {
                if (m < 8) {
#pragma unroll
                    for (int r = 0; r < 4; ++r)
                        mean_out[(R0 + quad * 4 + r) * 8 + m] = tacc[r];
                }
            } else {
                if (m == 8) {
#pragma unroll
                    for (int r = 0; r < 4; ++r)
                        val_out[R0 + quad * 4 + r] = tacc[r];
                }
            }
        }
    }

#pragma unroll
    for (int r = 0; r < 4; ++r)
        hT_out[((size_t)a * B_ + b0 + quad * 4 + r) * H_ + col] = hm[r];

    // epilogue: heads for ys(T-2) (al[1]) and ys(T-1) (fresh)
    {
        u16 (*hl)[136] = hlds[0];
#pragma unroll
        for (int r = 0; r < 4; ++r) hl[quad * 4 + r][col] = hb[r];
        __syncthreads();
        short8 af[4];
#pragma unroll
        for (int ks = 0; ks < 4; ++ks)
            af[ks] = *(const short8*)&hl[m][ks * 32 + quad * 8];
        f32x4 aa = f32x4{fa, fa, fa, fa};
        f32x4 ac = f32x4{fc, fc, fc, fc};
#pragma unroll
        for (int ks = 0; ks < 4; ++ks) {
            aa = mfma16(af[ks], wa[ks], aa);
            ac = mfma16(af[ks], wc[ks], ac);
        }
#pragma unroll
        for (int r = 0; r < 4; ++r) {
            al[0][0][quad * 4 + r][col] = f2bc(tanh_pre(aa[r]));
            al[0][1][quad * 4 + r][col] = f2bc(tanh_pre(ac[r]));
        }
        // GEMM2 for ys(T-2): al[(T-1)&1] = al[1], written at t=T-1
        if (wid < 2) {
            short8 tf[4];
#pragma unroll
            for (int ks = 0; ks < 4; ++ks)
                tf[ks] = *(const short8*)&al[1][wid][m][ks * 32 + quad * 8];
            f32x4 tacc = f32x4{bb2, bb2, bb2, bb2};
#pragma unroll
            for (int ks = 0; ks < 4; ++ks) tacc = mfma16(tf[ks], h2f[ks], tacc);
            const size_t R0 = (size_t)a * 32768 + (size_t)(T_ - 2) * 256 + b0;
            if (wid == 0) {
                if (m < 8) {
#pragma unroll
                    for (int r = 0; r < 4; ++r)
                        mean_out[(R0 + quad * 4 + r) * 8 + m] = tacc[r];
                }
            } else {
                if (m == 8) {
#pragma unroll
                    for (int r = 0; r < 4; ++r)
                        val_out[R0 + quad * 4 + r] = tacc[r];
                }
            }
        }
        __syncthreads();
        // GEMM2 for ys(T-1): al[0] written above
        if (wid < 2) {
            short8 tf[4];
#pragma unroll
            for (int ks = 0; ks < 4; ++ks)
                tf[ks] = *(const short8*)&al[0][wid][m][ks * 32 + quad * 8];
            f32x4 tacc = f32x4{bb2, bb2, bb2, bb2};
#pragma unroll
            for (int ks = 0; ks < 4; ++ks) tacc = mfma16(tf[ks], h2f[ks], tacc);
            const size_t R0 = (size_t)a * 32768 + (size_t)(T_ - 1) * 256 + b0;
            if (wid == 0) {
                if (m < 8) {
#pragma unroll
                    for (int r = 0; r < 4; ++r)
                        mean_out[(R0 + quad * 4 + r) * 8 + m] = tacc[r];
                }
            } else {
                if (m == 8) {
#pragma unroll
                    for (int r = 0; r < 4; ++r)
                        val_out[R0 + quad * 4 + r] = tacc[r];
                }
            }
        }
    }
}

extern "C" void kernel_launch(void* const* d_in, const int* in_sizes, int n_in,
                              void* d_out, int out_size, void* d_ws, size_t ws_size,
                              hipStream_t stream) {
    const float* hstate = (const float*)d_in[0];
    const float* obs = (const float*)d_in[1];
    const float* We = (const float*)d_in[3];
    const float* be = (const float*)d_in[4];
    const float* Wi = (const float*)d_in[5];
    const float* bi = (const float*)d_in[6];
    const float* Wh = (const float*)d_in[7];
    const float* bhn = (const float*)d_in[8];
    const float* Wa1 = (const float*)d_in[9];
    const float* ba1 = (const float*)d_in[10];
    const float* Wa2 = (const float*)d_in[11];
    const float* ba2 = (const float*)d_in[12];
    const float* log_std = (const float*)d_in[13];
    const float* Wc1 = (const float*)d_in[14];
    const float* bc1 = (const float*)d_in[15];
    const float* Wc2 = (const float*)d_in[16];
    const float* bc2 = (const float*)d_in[17];
    const int* done = (const int*)d_in[18];

    float* out = (float*)d_out;
    float* hT_out = out;                    // (4,256,128)
    float* mean_out = out + 131072;         // (4,128,256,8)
    float* std_out = out + 1179648;         // (4,8)
    float* val_out = out + 1179680;         // (4,128,256)

    u16* ws = (u16*)d_ws;
    u16* xi = ws;                           // unused now (layout preserved)
    u16* ys = xi + 50331648;                // unused
    u16* weT = ys + 16777216;
    u16* wiT = weT + 65536;
    u16* whT = wiT + 196608;
    u16* wa1T = whT + 196608;
    u16* wc1T = wa1T + 65536;
    u16* h2T = wc1T + 65536;

    hipLaunchKernelGGL(k_prep, dim3(2337), dim3(256), 0, stream,
                       We, Wi, Wh, Wa1, Wc1, Wa2, Wc2, log_std,
                       weT, wiT, whT, wa1T, wc1T, h2T, std_out);
    hipLaunchKernelGGL(k_scan, dim3(16, 4), dim3(512), 0, stream,
                       hstate, obs, weT, wiT, whT, be, bi, bhn, done,
                       wa1T, wc1T, h2T, ba1, bc1, ba2, bc2,
                       hT_out, mean_out, val_out);
}